// Round 21
// baseline (85.179 us; speedup 1.0000x reference)
//
#include <hip/hip_runtime.h>
#include <math.h>

#define DD 768
#define NN 64
#define SS 512
#define BB 4
#define BSD (BB * SS * DD)

__device__ __forceinline__ float sigmf(float v) { return 1.0f / (1.0f + expf(-v)); }

// ---- DPP add helper (bound_ctrl=0-fill) ----
template <int CTRL>
__device__ __forceinline__ float dppadd(float v) {
    int s = __builtin_amdgcn_update_dpp(0, __float_as_int(v), CTRL, 0xF, 0xF, true);
    return v + __int_as_float(s);
}
__device__ __forceinline__ float row_sum15(float v) {
    v = dppadd<0x111>(v);
    v = dppadd<0x112>(v);
    v = dppadd<0x114>(v);
    v = dppadd<0x118>(v);
    return v;              // valid in lane 15 of each 16-lane row
}
__device__ __forceinline__ float wave_sum63(float v) {
    v = row_sum15(v);
    v = dppadd<0x142>(v);
    v = dppadd<0x143>(v);
    return v;
}

// ---- prep: BwT[d][n] = sigmoid(Braw[n][d]) via LDS tile; gamma (12 blocks) ----
__global__ __launch_bounds__(256) void prep_kernel(const float* __restrict__ Braw,
                                                   const float* __restrict__ graw,
                                                   float* __restrict__ BwT,
                                                   float* __restrict__ gamma_s) {
    __shared__ float tile[64][65];
    int tx = threadIdx.x & 63;
    int tq = threadIdx.x >> 6;
    int d0 = blockIdx.x * 64;
#pragma unroll
    for (int i = 0; i < 16; ++i) {
        int n = tq + i * 4;
        tile[n][tx] = sigmf(Braw[n * DD + d0 + tx]);
    }
    __syncthreads();
#pragma unroll
    for (int i = 0; i < 16; ++i) {
        int dl = tq + i * 4;
        BwT[(d0 + dl) * NN + tx] = tile[tx][dl];
    }
    int gi = blockIdx.x * 256 + threadIdx.x;
    if (gi < DD) gamma_s[gi] = sigmf(graw[gi]);
}

// ---- fused: blocks 0..511 = inp (LDS-staged BwT, linear store);
//      blocks 512..895 = x-transpose tiles. Independent work, overlapped. ----
__global__ __launch_bounds__(256, 2) void inp_xpose_kernel(const float* __restrict__ x,
                                                           const float* __restrict__ BwT,
                                                           float* __restrict__ inp,
                                                           float* __restrict__ xT) {
    __shared__ float4 smem[2048];   // 32 KiB

    if (blockIdx.x < 512) {
        float4* bwlds0 = smem;
        float4* bwlds1 = smem + 1024;
        int w    = threadIdx.x >> 6;
        int lane = threadIdx.x & 63;
        int g = lane >> 4;
        int q = lane & 15;
        int r = blockIdx.x * 4 + w;
        const float*  xr  = x + (size_t)r * DD;
        const float4* bwg = (const float4*)BwT;

#pragma unroll
        for (int k = 0; k < 4; ++k)
            bwlds0[threadIdx.x + k * 256] = bwg[threadIdx.x + k * 256];
        __syncthreads();

        float4 acc = {0.f, 0.f, 0.f, 0.f};
        for (int c = 0; c < 12; ++c) {
            float4* cur = (c & 1) ? bwlds1 : bwlds0;
            float4* nxt = (c & 1) ? bwlds0 : bwlds1;
            float4 s0, s1, s2, s3;
            if (c < 11) {
                int base = (c + 1) * 1024 + threadIdx.x;
                s0 = bwg[base];
                s1 = bwg[base + 256];
                s2 = bwg[base + 512];
                s3 = bwg[base + 768];
            }
            int d0 = c * 64;
#pragma unroll
            for (int jj = 0; jj < 4; ++jj) {
                int dbase = jj * 16 + g;
                float x0 = xr[d0 + dbase + 0];
                float x1 = xr[d0 + dbase + 4];
                float x2 = xr[d0 + dbase + 8];
                float x3 = xr[d0 + dbase + 12];
                float4 w0 = cur[(dbase + 0) * 16 + q];
                float4 w1 = cur[(dbase + 4) * 16 + q];
                float4 w2 = cur[(dbase + 8) * 16 + q];
                float4 w3 = cur[(dbase + 12) * 16 + q];
#define IFMA(W, X)                       \
    acc.x = fmaf(X, W.x, acc.x);         \
    acc.y = fmaf(X, W.y, acc.y);         \
    acc.z = fmaf(X, W.z, acc.z);         \
    acc.w = fmaf(X, W.w, acc.w);
                IFMA(w0, x0) IFMA(w1, x1) IFMA(w2, x2) IFMA(w3, x3)
            }
            if (c < 11) {
                nxt[threadIdx.x]       = s0;
                nxt[threadIdx.x + 256] = s1;
                nxt[threadIdx.x + 512] = s2;
                nxt[threadIdx.x + 768] = s3;
            }
            __syncthreads();
        }

#pragma unroll
        for (int off = 16; off <= 32; off <<= 1) {
            acc.x += __shfl_xor(acc.x, off, 64);
            acc.y += __shfl_xor(acc.y, off, 64);
            acc.z += __shfl_xor(acc.z, off, 64);
            acc.w += __shfl_xor(acc.w, off, 64);
        }
        if (lane < 16) ((float4*)(inp + (size_t)r * NN))[q] = acc;
    } else {
        float* tile = (float*)smem;   // [64][65] view
        int bidx = blockIdx.x - 512;  // 0..383
        int b  = bidx / 96;
        int r  = bidx - b * 96;
        int t0 = (r / 12) * 64;
        int d0 = (r % 12) * 64;
        int tx = threadIdx.x & 63;
        int tq = threadIdx.x >> 6;
#pragma unroll
        for (int i = 0; i < 16; ++i) {
            int t = tq + i * 4;
            tile[t * 65 + tx] = x[((size_t)b * SS + t0 + t) * DD + d0 + tx];
        }
        __syncthreads();
#pragma unroll
        for (int i = 0; i < 16; ++i) {
            int dl = tq + i * 4;
            xT[((size_t)b * DD + d0 + dl) * SS + t0 + tx] = tile[tx * 65 + dl];
        }
    }
}

// ---- phase 2: scan v16 = R11's proven form (K=1 scalar, chunk-8 batched,
// register consume — VGPR 36, no sinking; 4-wave = 4 n-quarters, per-chunk
// LDS combine) x 2 time-halves via recompute. Block = (b, dg, half); half=1
// runs a 256-step h-only preamble (3 instr/step, no LDS) then produces y for
// t=256..511. 1536 blocks = 6144 waves = 6/SIMD (was 3).
__global__ __launch_bounds__(256) void scan_kernel(const float* __restrict__ xT,
                                                   const float* __restrict__ Araw,
                                                   const float* __restrict__ Craw,
                                                   const float* __restrict__ inp,
                                                   float* __restrict__ Y,
                                                   float* __restrict__ hfin) {
    int p    = threadIdx.x >> 6;        // n-quarter 0..3 (wave within block)
    int lane = threadIdx.x & 63;
    int dl = lane >> 4;                 // d within group, 0..3
    int ng = lane & 15;
    int half = blockIdx.x & 1;
    int gb   = blockIdx.x >> 1;         // 0..767
    int b  = gb / 192;
    int dg = gb - b * 192;              // d-group 0..191
    int d  = dg * 4 + dl;
    int n  = p * 16 + ng;

    float a = sigmf(Araw[(size_t)d * NN + n]);
    float c = sigmf(Craw[(size_t)d * NN + n]);

    const float*  ip_ptr = inp + (size_t)(b * SS) * NN + n;                // [t*64]
    const float4* xt4    = (const float4*)(xT + ((size_t)b * DD + d) * SS);
    float*        y_blk  = Y + (size_t)(b * SS) * DD + dg * 4;

    __shared__ float lds[2][4][4][8];   // [slab][p][dl][i] = 1 KiB

    float Ai[8], Bi[8];
    float4 Ax0, Ax1, Bx0, Bx1;
    float h = 0.f;

#define SPREF(P, T0)                                                       \
    {                                                                      \
        int tt_ = ((T0) < SS) ? (T0) : 0;                                  \
        _Pragma("unroll")                                                  \
        for (int i_ = 0; i_ < 8; ++i_) P##i[i_] = ip_ptr[(tt_ + i_) * NN]; \
        P##x0 = xt4[(tt_ >> 2) + 0];                                       \
        P##x1 = xt4[(tt_ >> 2) + 1];                                       \
    }
#define HCH(P)                                                                   \
    {                                                                            \
        const float xs_[8] = {P##x0.x, P##x0.y, P##x0.z, P##x0.w,                \
                              P##x1.x, P##x1.y, P##x1.z, P##x1.w};               \
        _Pragma("unroll")                                                        \
        for (int i_ = 0; i_ < 8; ++i_)                                           \
            h = __builtin_amdgcn_fmed3f(fmaf(h, a, P##i[i_] * xs_[i_]), 0.f, 1.f); \
    }
#define SCHUNK(P, T0, SL)                                                        \
    {                                                                            \
        const float xs_[8] = {P##x0.x, P##x0.y, P##x0.z, P##x0.w,                \
                              P##x1.x, P##x1.y, P##x1.z, P##x1.w};               \
        float hs_[8];                                                            \
        _Pragma("unroll")                                                        \
        for (int i_ = 0; i_ < 8; ++i_) {                                         \
            h = __builtin_amdgcn_fmed3f(fmaf(h, a, P##i[i_] * xs_[i_]), 0.f, 1.f); \
            hs_[i_] = h;                                                         \
        }                                                                        \
        float ps_[8];                                                            \
        _Pragma("unroll")                                                        \
        for (int i_ = 0; i_ < 8; ++i_) ps_[i_] = hs_[i_] * c;                    \
        _Pragma("unroll")                                                        \
        for (int i_ = 0; i_ < 8; ++i_) ps_[i_] = row_sum15(ps_[i_]);             \
        if (ng == 15) {                                                          \
            _Pragma("unroll")                                                    \
            for (int i_ = 0; i_ < 8; ++i_) lds[SL][p][dl][i_] = ps_[i_];         \
        }                                                                        \
        __syncthreads();                                                         \
        if (threadIdx.x < 32) {                                                  \
            int i_  = threadIdx.x >> 2;                                          \
            int dli = threadIdx.x & 3;                                           \
            float v_ = (lds[SL][0][dli][i_] + lds[SL][1][dli][i_]) +             \
                       (lds[SL][2][dli][i_] + lds[SL][3][dli][i_]);              \
            y_blk[((T0) + i_) * DD + dli] = v_;                                  \
        }                                                                        \
    }

    if (half) {
        // h-only preamble over t = 0..255 (identical op order; no LDS/barriers)
        SPREF(A, 0)
        SPREF(B, 8)
        for (int t0 = 0; t0 < 256; t0 += 16) {
            HCH(A) SPREF(A, t0 + 16)
            HCH(B) SPREF(B, t0 + 24)
        }
    }

    int tb = half * 256;
    SPREF(A, tb)
    SPREF(B, tb + 8)
    for (int t0 = tb; t0 < tb + 256; t0 += 16) {
        SCHUNK(A, t0, 0)
        SPREF(A, t0 + 16)
        SCHUNK(B, t0 + 8, 1)
        SPREF(B, t0 + 24)
    }
    if (half) hfin[((size_t)b * DD + d) * NN + n] = h;
}

// ---- fallback scan (no xT; strided x reads; linear inp) ----
__global__ __launch_bounds__(256) void scan_fb_kernel(const float* __restrict__ x,
                                                      const float* __restrict__ Araw,
                                                      const float* __restrict__ Craw,
                                                      const float* __restrict__ inp,
                                                      float* __restrict__ Y,
                                                      float* __restrict__ hfin) {
    int wid  = (blockIdx.x * 256 + threadIdx.x) >> 6;
    int lane = threadIdx.x & 63;
    int b = wid / DD;
    int d = wid - b * DD;

    float a = sigmf(Araw[d * NN + lane]);
    float c = sigmf(Craw[d * NN + lane]);

    const float* ip_ptr = inp + (b * SS) * NN + lane;
    const float* x_ptr  = x   + (b * SS) * DD + d;
    float*       y_ptr  = Y   + (b * SS) * DD + d;

    float cip[8], cxv[8], nip[8], nxv[8];
#pragma unroll
    for (int i = 0; i < 8; ++i) {
        cip[i] = ip_ptr[i * NN];
        cxv[i] = x_ptr[i * DD];
    }
    float h = 0.f;
    for (int t0 = 0; t0 < SS; t0 += 8) {
        int tn = t0 + 8;
        if (tn >= SS) tn = SS - 8;
#pragma unroll
        for (int i = 0; i < 8; ++i) {
            nip[i] = ip_ptr[(tn + i) * NN];
            nxv[i] = x_ptr[(tn + i) * DD];
        }
#pragma unroll
        for (int i = 0; i < 8; ++i) {
            h = __builtin_amdgcn_fmed3f(fmaf(h, a, cip[i] * cxv[i]), 0.f, 1.f);
            float v = wave_sum63(h * c);
            if (lane == 63) y_ptr[(t0 + i) * DD] = v;
        }
#pragma unroll
        for (int i = 0; i < 8; ++i) { cip[i] = nip[i]; cxv[i] = nxv[i]; }
    }
    hfin[(size_t)wid * NN + lane] = h;
}

// ---- phase 3: in-place layernorm + gamma + residual + clip (float4) ----
__global__ __launch_bounds__(256) void ln_kernel(const float* __restrict__ x,
                                                 const float* __restrict__ gamma_s,
                                                 float* __restrict__ out) {
    int wid  = (blockIdx.x * 256 + threadIdx.x) >> 6;
    int lane = threadIdx.x & 63;
    float*       yr = out + (size_t)wid * DD;
    const float* xr = x   + (size_t)wid * DD;

    float4 y0 = ((const float4*)yr)[lane * 3 + 0];
    float4 y1 = ((const float4*)yr)[lane * 3 + 1];
    float4 y2 = ((const float4*)yr)[lane * 3 + 2];

    float s = ((y0.x + y0.y) + (y0.z + y0.w)) + ((y1.x + y1.y) + (y1.z + y1.w)) +
              ((y2.x + y2.y) + (y2.z + y2.w));
#pragma unroll
    for (int off = 32; off; off >>= 1) s += __shfl_xor(s, off, 64);
    float mu = s * (1.f / 768.f);

    float q = 0.f;
#define QACC(v)                 \
    {                           \
        float d0_ = (v) - mu;   \
        q = fmaf(d0_, d0_, q);  \
    }
    QACC(y0.x) QACC(y0.y) QACC(y0.z) QACC(y0.w)
    QACC(y1.x) QACC(y1.y) QACC(y1.z) QACC(y1.w)
    QACC(y2.x) QACC(y2.y) QACC(y2.z) QACC(y2.w)
#pragma unroll
    for (int off = 32; off; off >>= 1) q += __shfl_xor(q, off, 64);
    float inv = rsqrtf(q * (1.f / 768.f) + 1e-5f);

    float4 g0 = ((const float4*)gamma_s)[lane * 3 + 0];
    float4 g1 = ((const float4*)gamma_s)[lane * 3 + 1];
    float4 g2 = ((const float4*)gamma_s)[lane * 3 + 2];
    float4 x0 = ((const float4*)xr)[lane * 3 + 0];
    float4 x1 = ((const float4*)xr)[lane * 3 + 1];
    float4 x2 = ((const float4*)xr)[lane * 3 + 2];

#define FIN(yv, gv, xv) __builtin_amdgcn_fmed3f(fmaf((yv - mu) * inv, gv, xv), 0.f, 1.f)
    float4 o0, o1, o2;
    o0.x = FIN(y0.x, g0.x, x0.x); o0.y = FIN(y0.y, g0.y, x0.y);
    o0.z = FIN(y0.z, g0.z, x0.z); o0.w = FIN(y0.w, g0.w, x0.w);
    o1.x = FIN(y1.x, g1.x, x1.x); o1.y = FIN(y1.y, g1.y, x1.y);
    o1.z = FIN(y1.z, g1.z, x1.z); o1.w = FIN(y1.w, g1.w, x1.w);
    o2.x = FIN(y2.x, g2.x, x2.x); o2.y = FIN(y2.y, g2.y, x2.y);
    o2.z = FIN(y2.z, g2.z, x2.z); o2.w = FIN(y2.w, g2.w, x2.w);

    ((float4*)yr)[lane * 3 + 0] = o0;
    ((float4*)yr)[lane * 3 + 1] = o1;
    ((float4*)yr)[lane * 3 + 2] = o2;
}

extern "C" void kernel_launch(void* const* d_in, const int* in_sizes, int n_in,
                              void* d_out, int out_size, void* d_ws, size_t ws_size,
                              hipStream_t stream) {
    const float* x    = (const float*)d_in[0];  // [B,S,D]
    const float* Araw = (const float*)d_in[1];  // [D,N]
    const float* Braw = (const float*)d_in[2];  // [N,D]
    const float* Craw = (const float*)d_in[3];  // [D,N]
    const float* graw = (const float*)d_in[4];  // [D]

    float* out  = (float*)d_out;                // [B,S,D] then [B,D,N]
    float* hfin = out + (size_t)BSD;

    float* ws      = (float*)d_ws;
    float* BwT     = ws;                                   // D*N   = 49152
    float* gamma_s = ws + DD * NN;                         // D     = 768
    float* inp     = ws + DD * NN + DD;                    // B*S*N = 131072
    float* xT      = ws + DD * NN + DD + BB * SS * NN;     // B*D*S = 1572864

    size_t need = (size_t)(DD * NN + DD + (size_t)BB * SS * NN + (size_t)BSD) * sizeof(float);

    if (ws_size >= need) {
        prep_kernel<<<DD / 64, 256, 0, stream>>>(Braw, graw, BwT, gamma_s);
        inp_xpose_kernel<<<512 + BB * (SS / 64) * (DD / 64), 256, 0, stream>>>(
            x, BwT, inp, xT);
        // 1536 blocks: (b, dg) x 2 time-halves; 4 waves/block = 4 n-quarters
        scan_kernel<<<BB * (DD / 4) * 2, 256, 0, stream>>>(xT, Araw, Craw, inp, out, hfin);
    } else {
        prep_kernel<<<DD / 64, 256, 0, stream>>>(Braw, graw, BwT, gamma_s);
        inp_xpose_kernel<<<512 + BB * (SS / 64) * (DD / 64), 256, 0, stream>>>(
            x, BwT, inp, xT);
        scan_fb_kernel<<<(BB * DD * NN) / 256, 256, 0, stream>>>(x, Araw, Craw, inp, out, hfin);
    }
    ln_kernel<<<(BB * SS * NN) / 256, 256, 0, stream>>>(x, gamma_s, out);
}

// Round 23
// 60.202 us; speedup vs baseline: 1.4149x; 1.4149x over previous
//
#include <hip/hip_runtime.h>
#include <math.h>

#define DD 768
#define NN 64
#define SS 512
#define BB 4
#define BSD (BB * SS * DD)

__device__ __forceinline__ float sigmf(float v) { return 1.0f / (1.0f + expf(-v)); }

// ---- DPP add helper (bound_ctrl=0-fill) ----
template <int CTRL>
__device__ __forceinline__ float dppadd(float v) {
    int s = __builtin_amdgcn_update_dpp(0, __float_as_int(v), CTRL, 0xF, 0xF, true);
    return v + __int_as_float(s);
}
__device__ __forceinline__ float row_sum15(float v) {
    v = dppadd<0x111>(v);
    v = dppadd<0x112>(v);
    v = dppadd<0x114>(v);
    v = dppadd<0x118>(v);
    return v;              // valid in lane 15 of each 16-lane row
}
__device__ __forceinline__ float wave_sum63(float v) {
    v = row_sum15(v);
    v = dppadd<0x142>(v);  // row_bcast:15
    v = dppadd<0x143>(v);  // row_bcast:31
    return v;
}

// ---- fused prep (blocks 0..11) + x-transpose (blocks 12..395) ----
__global__ __launch_bounds__(256) void prep_xpose_kernel(const float* __restrict__ Braw,
                                                         const float* __restrict__ graw,
                                                         const float* __restrict__ x,
                                                         float* __restrict__ BwT,
                                                         float* __restrict__ gamma_s,
                                                         float* __restrict__ xT) {
    __shared__ float tile[64][65];
    int tx = threadIdx.x & 63;
    int tq = threadIdx.x >> 6;  // 0..3
    if (blockIdx.x < 12) {
        int d0 = blockIdx.x * 64;
#pragma unroll
        for (int i = 0; i < 16; ++i) {
            int n = tq + i * 4;
            tile[n][tx] = sigmf(Braw[n * DD + d0 + tx]);
        }
        __syncthreads();
#pragma unroll
        for (int i = 0; i < 16; ++i) {
            int dl = tq + i * 4;
            BwT[(d0 + dl) * NN + tx] = tile[tx][dl];
        }
        int gi = blockIdx.x * 256 + threadIdx.x;
        if (gi < DD) gamma_s[gi] = sigmf(graw[gi]);
    } else {
        int bidx = blockIdx.x - 12;
        int b  = bidx / 96;
        int r  = bidx - b * 96;
        int t0 = (r / 12) * 64;
        int d0 = (r % 12) * 64;
#pragma unroll
        for (int i = 0; i < 16; ++i) {
            int t = tq + i * 4;
            tile[t][tx] = x[((size_t)b * SS + t0 + t) * DD + d0 + tx];
        }
        __syncthreads();
#pragma unroll
        for (int i = 0; i < 16; ++i) {
            int dl = tq + i * 4;
            xT[((size_t)b * DD + d0 + dl) * SS + t0 + tx] = tile[tx][dl];
        }
    }
}

// ---- phase 1 (R14/R15-proven): LDS-staged BwT; TILED store
// inpT[b][t>>3][n][t&7] so scan reads 2x b128 per 8 steps, coalesced.
__global__ __launch_bounds__(256, 2) void inp_kernel(const float* __restrict__ x,
                                                     const float* __restrict__ BwT,
                                                     float* __restrict__ inp) {
    int w    = threadIdx.x >> 6;   // row within block
    int lane = threadIdx.x & 63;
    int g = lane >> 4;             // d-subgroup
    int q = lane & 15;             // n-quad
    int r = blockIdx.x * 4 + w;
    const float*  xr  = x + (size_t)r * DD;
    const float4* bwg = (const float4*)BwT;   // float4 index = d*16 + c4

    __shared__ float4 bwlds[2][1024];  // [buf][d*16 + c4], 2 x 16 KiB

#pragma unroll
    for (int k = 0; k < 4; ++k)
        bwlds[0][threadIdx.x + k * 256] = bwg[threadIdx.x + k * 256];
    __syncthreads();

    float4 acc = {0.f, 0.f, 0.f, 0.f};
    for (int c = 0; c < 12; ++c) {
        int cur = c & 1;
        float4 s0, s1, s2, s3;
        if (c < 11) {
            int base = (c + 1) * 1024 + threadIdx.x;
            s0 = bwg[base];
            s1 = bwg[base + 256];
            s2 = bwg[base + 512];
            s3 = bwg[base + 768];
        }
        int d0 = c * 64;
#pragma unroll
        for (int jj = 0; jj < 4; ++jj) {
            int dbase = jj * 16 + g;
            float x0 = xr[d0 + dbase + 0];
            float x1 = xr[d0 + dbase + 4];
            float x2 = xr[d0 + dbase + 8];
            float x3 = xr[d0 + dbase + 12];
            float4 w0 = bwlds[cur][(dbase + 0) * 16 + q];
            float4 w1 = bwlds[cur][(dbase + 4) * 16 + q];
            float4 w2 = bwlds[cur][(dbase + 8) * 16 + q];
            float4 w3 = bwlds[cur][(dbase + 12) * 16 + q];
#define IFMA(W, X)                       \
    acc.x = fmaf(X, W.x, acc.x);         \
    acc.y = fmaf(X, W.y, acc.y);         \
    acc.z = fmaf(X, W.z, acc.z);         \
    acc.w = fmaf(X, W.w, acc.w);
            IFMA(w0, x0) IFMA(w1, x1) IFMA(w2, x2) IFMA(w3, x3)
        }
        if (c < 11) {
            int nb = cur ^ 1;
            bwlds[nb][threadIdx.x]       = s0;
            bwlds[nb][threadIdx.x + 256] = s1;
            bwlds[nb][threadIdx.x + 512] = s2;
            bwlds[nb][threadIdx.x + 768] = s3;
        }
        __syncthreads();
    }

#pragma unroll
    for (int off = 16; off <= 32; off <<= 1) {
        acc.x += __shfl_xor(acc.x, off, 64);
        acc.y += __shfl_xor(acc.y, off, 64);
        acc.z += __shfl_xor(acc.z, off, 64);
        acc.w += __shfl_xor(acc.w, off, 64);
    }
    if (lane < 16) {
        int bb = r >> 9;            // r / 512
        int tt = r & 511;
        // element (bb, tt, n) -> inp[((bb*64 + tt>>3)*64 + n)*8 + (tt&7)]
        float* dst = inp + ((size_t)bb * 64 + (tt >> 3)) * 512 + (tt & 7);
        dst[(4 * q + 0) * 8] = acc.x;
        dst[(4 * q + 1) * 8] = acc.y;
        dst[(4 * q + 2) * 8] = acc.z;
        dst[(4 * q + 3) * 8] = acc.w;
    }
}

// ---- phase 2: scan v12 (best-known-good, R17 = 60.2us total). Single-phase;
// wave = one d x 64 n (lane = n); 768 blocks x 4 waves. ip staged through LDS
// with issue-early / write-late split; 4-slab ring, static indices.
__global__ __launch_bounds__(256) void scan_kernel(const float* __restrict__ xT,
                                                   const float* __restrict__ Araw,
                                                   const float* __restrict__ Craw,
                                                   const float* __restrict__ inpT,
                                                   float* __restrict__ Y,
                                                   float* __restrict__ hfin) {
    int w    = threadIdx.x >> 6;        // wave in block = d-sub
    int lane = threadIdx.x & 63;        // n
    int gb = blockIdx.x;                // 0..767
    int b  = gb / 192;
    int dg = gb - b * 192;
    int d  = dg * 4 + w;

    float a = sigmf(Araw[(size_t)d * NN + lane]);
    float c = sigmf(Craw[(size_t)d * NN + lane]);

    const float*  ipT = inpT + (size_t)b * (SS / 8) * NN * 8;   // b*32768
    const float4* xt4 = (const float4*)(xT + ((size_t)b * DD + d) * SS);
    float*        y_d = Y + (size_t)(b * SS) * DD + d;

    __shared__ float ipst[4][4][8][64];  // [wave][slab][step][n] = 32 KiB

    int s8 = lane >> 3;   // staged step this lane reduces
    int j8 = lane & 7;    // 8-value slice within that step

    float h = 0.f;
    float4 pA0, pA1, pB0, pB1, pC0, pC1, pD0, pD1;
    float4 xA0, xA1, xB0, xB1, xC0, xC1, xD0, xD1;

#define PRELOAD(CH, PV0, PV1, XV0, XV1)                                    \
    {                                                                      \
        int ch_ = ((CH) < 64) ? (CH) : 0;                                  \
        const float4* pp_ = (const float4*)(ipT + (ch_ * 64 + lane) * 8);  \
        PV0 = pp_[0];                                                      \
        PV1 = pp_[1];                                                      \
        XV0 = xt4[ch_ * 2];                                                \
        XV1 = xt4[ch_ * 2 + 1];                                            \
    }
#define STAGE(SL, PV0, PV1)                                                \
    {                                                                      \
        ipst[w][SL][0][lane] = PV0.x;                                      \
        ipst[w][SL][1][lane] = PV0.y;                                      \
        ipst[w][SL][2][lane] = PV0.z;                                      \
        ipst[w][SL][3][lane] = PV0.w;                                      \
        ipst[w][SL][4][lane] = PV1.x;                                      \
        ipst[w][SL][5][lane] = PV1.y;                                      \
        ipst[w][SL][6][lane] = PV1.z;                                      \
        ipst[w][SL][7][lane] = PV1.w;                                      \
    }
#define CONSUME(SL, XV0, XV1, CC)                                                 \
    {                                                                             \
        const float xs_[8] = {XV0.x, XV0.y, XV0.z, XV0.w,                         \
                              XV1.x, XV1.y, XV1.z, XV1.w};                        \
        _Pragma("unroll")                                                         \
        for (int i_ = 0; i_ < 8; ++i_) {                                          \
            float ipv_ = ipst[w][SL][i_][lane];                                   \
            h = __builtin_amdgcn_fmed3f(fmaf(h, a, ipv_ * xs_[i_]), 0.f, 1.f);    \
            ipst[w][SL][i_][lane] = h * c;   /* in-place h*c for reduce */        \
        }                                                                         \
        float4 v0_ = *(const float4*)&ipst[w][SL][s8][j8 * 8];                    \
        float4 v1_ = *(const float4*)&ipst[w][SL][s8][j8 * 8 + 4];                \
        float s_ = ((v0_.x + v0_.y) + (v0_.z + v0_.w)) +                          \
                   ((v1_.x + v1_.y) + (v1_.z + v1_.w));                           \
        s_ = dppadd<0x111>(s_);                                                   \
        s_ = dppadd<0x112>(s_);                                                   \
        s_ = dppadd<0x114>(s_);                                                   \
        if (j8 == 7) y_d[((CC) * 8 + s8) * DD] = s_;                              \
    }

    // prologue: stage chunks 0 and 1 into slabs 0,1; xv regs A,B
    PRELOAD(0, pA0, pA1, xA0, xA1)
    STAGE(0, pA0, pA1)
    PRELOAD(1, pB0, pB1, xB0, xB1)
    STAGE(1, pB0, pB1)

    for (int cb = 0; cb < 64; cb += 4) {
        PRELOAD(cb + 2, pC0, pC1, xC0, xC1)
        CONSUME(0, xA0, xA1, cb + 0)
        STAGE(2, pC0, pC1)

        PRELOAD(cb + 3, pD0, pD1, xD0, xD1)
        CONSUME(1, xB0, xB1, cb + 1)
        STAGE(3, pD0, pD1)

        PRELOAD(cb + 4, pA0, pA1, xA0, xA1)
        CONSUME(2, xC0, xC1, cb + 2)
        STAGE(0, pA0, pA1)

        PRELOAD(cb + 5, pB0, pB1, xB0, xB1)
        CONSUME(3, xD0, xD1, cb + 3)
        STAGE(1, pB0, pB1)
    }
    hfin[((size_t)b * DD + d) * NN + lane] = h;
}

// ---- fallback scan (no xT; strided x reads; 1-n-per-lane; tiled inp) ----
__global__ __launch_bounds__(256) void scan_fb_kernel(const float* __restrict__ x,
                                                      const float* __restrict__ Araw,
                                                      const float* __restrict__ Craw,
                                                      const float* __restrict__ inpT,
                                                      float* __restrict__ Y,
                                                      float* __restrict__ hfin) {
    int wid  = (blockIdx.x * 256 + threadIdx.x) >> 6;
    int lane = threadIdx.x & 63;
    int b = wid / DD;
    int d = wid - b * DD;

    float a = sigmf(Araw[d * NN + lane]);
    float c = sigmf(Craw[d * NN + lane]);

    const float* ipT   = inpT + (size_t)b * (SS / 8) * NN * 8;
    const float* x_ptr = x + (b * SS) * DD + d;
    float*       y_ptr = Y + (b * SS) * DD + d;

#define IPAT(T) ipT[(((T) >> 3) * 64 + lane) * 8 + ((T) & 7)]

    float cip[8], cxv[8], nip[8], nxv[8];
#pragma unroll
    for (int i = 0; i < 8; ++i) {
        cip[i] = IPAT(i);
        cxv[i] = x_ptr[i * DD];
    }
    float h = 0.f;
    for (int t0 = 0; t0 < SS; t0 += 8) {
        int tn = t0 + 8;
        if (tn >= SS) tn = SS - 8;
#pragma unroll
        for (int i = 0; i < 8; ++i) {
            nip[i] = IPAT(tn + i);
            nxv[i] = x_ptr[(tn + i) * DD];
        }
#pragma unroll
        for (int i = 0; i < 8; ++i) {
            h = __builtin_amdgcn_fmed3f(fmaf(h, a, cip[i] * cxv[i]), 0.f, 1.f);
            float v = wave_sum63(h * c);
            if (lane == 63) y_ptr[(t0 + i) * DD] = v;
        }
#pragma unroll
        for (int i = 0; i < 8; ++i) { cip[i] = nip[i]; cxv[i] = nxv[i]; }
    }
    hfin[(size_t)wid * NN + lane] = h;
}

// ---- phase 3: in-place layernorm + gamma + residual + clip (float4) ----
__global__ __launch_bounds__(256) void ln_kernel(const float* __restrict__ x,
                                                 const float* __restrict__ gamma_s,
                                                 float* __restrict__ out) {
    int wid  = (blockIdx.x * 256 + threadIdx.x) >> 6;
    int lane = threadIdx.x & 63;
    float*       yr = out + (size_t)wid * DD;
    const float* xr = x   + (size_t)wid * DD;

    float4 y0 = ((const float4*)yr)[lane * 3 + 0];
    float4 y1 = ((const float4*)yr)[lane * 3 + 1];
    float4 y2 = ((const float4*)yr)[lane * 3 + 2];

    float s = ((y0.x + y0.y) + (y0.z + y0.w)) + ((y1.x + y1.y) + (y1.z + y1.w)) +
              ((y2.x + y2.y) + (y2.z + y2.w));
#pragma unroll
    for (int off = 32; off; off >>= 1) s += __shfl_xor(s, off, 64);
    float mu = s * (1.f / 768.f);

    float q = 0.f;
#define QACC(v)                 \
    {                           \
        float d0_ = (v) - mu;   \
        q = fmaf(d0_, d0_, q);  \
    }
    QACC(y0.x) QACC(y0.y) QACC(y0.z) QACC(y0.w)
    QACC(y1.x) QACC(y1.y) QACC(y1.z) QACC(y1.w)
    QACC(y2.x) QACC(y2.y) QACC(y2.z) QACC(y2.w)
#pragma unroll
    for (int off = 32; off; off >>= 1) q += __shfl_xor(q, off, 64);
    float inv = rsqrtf(q * (1.f / 768.f) + 1e-5f);

    float4 g0 = ((const float4*)gamma_s)[lane * 3 + 0];
    float4 g1 = ((const float4*)gamma_s)[lane * 3 + 1];
    float4 g2 = ((const float4*)gamma_s)[lane * 3 + 2];
    float4 x0 = ((const float4*)xr)[lane * 3 + 0];
    float4 x1 = ((const float4*)xr)[lane * 3 + 1];
    float4 x2 = ((const float4*)xr)[lane * 3 + 2];

#define FIN(yv, gv, xv) __builtin_amdgcn_fmed3f(fmaf((yv - mu) * inv, gv, xv), 0.f, 1.f)
    float4 o0, o1, o2;
    o0.x = FIN(y0.x, g0.x, x0.x); o0.y = FIN(y0.y, g0.y, x0.y);
    o0.z = FIN(y0.z, g0.z, x0.z); o0.w = FIN(y0.w, g0.w, x0.w);
    o1.x = FIN(y1.x, g1.x, x1.x); o1.y = FIN(y1.y, g1.y, x1.y);
    o1.z = FIN(y1.z, g1.z, x1.z); o1.w = FIN(y1.w, g1.w, x1.w);
    o2.x = FIN(y2.x, g2.x, x2.x); o2.y = FIN(y2.y, g2.y, x2.y);
    o2.z = FIN(y2.z, g2.z, x2.z); o2.w = FIN(y2.w, g2.w, x2.w);

    ((float4*)yr)[lane * 3 + 0] = o0;
    ((float4*)yr)[lane * 3 + 1] = o1;
    ((float4*)yr)[lane * 3 + 2] = o2;
}

extern "C" void kernel_launch(void* const* d_in, const int* in_sizes, int n_in,
                              void* d_out, int out_size, void* d_ws, size_t ws_size,
                              hipStream_t stream) {
    const float* x    = (const float*)d_in[0];  // [B,S,D]
    const float* Araw = (const float*)d_in[1];  // [D,N]
    const float* Braw = (const float*)d_in[2];  // [N,D]
    const float* Craw = (const float*)d_in[3];  // [D,N]
    const float* graw = (const float*)d_in[4];  // [D]

    float* out  = (float*)d_out;                // [B,S,D] then [B,D,N]
    float* hfin = out + (size_t)BSD;

    float* ws      = (float*)d_ws;
    float* BwT     = ws;                                   // D*N   = 49152
    float* gamma_s = ws + DD * NN;                         // D     = 768
    float* inp     = ws + DD * NN + DD;                    // B*S*N = 131072 (tiled)
    float* xT      = ws + DD * NN + DD + BB * SS * NN;     // B*D*S = 1572864

    size_t need = (size_t)(DD * NN + DD + (size_t)BB * SS * NN + (size_t)BSD) * sizeof(float);

    if (ws_size >= need) {
        prep_xpose_kernel<<<12 + BB * (SS / 64) * (DD / 64), 256, 0, stream>>>(
            Braw, graw, x, BwT, gamma_s, xT);
        inp_kernel<<<(BB * SS) / 4, 256, 0, stream>>>(x, BwT, inp);
        scan_kernel<<<BB * (DD / 4), 256, 0, stream>>>(xT, Araw, Craw, inp, out, hfin);
    } else {
        prep_xpose_kernel<<<12, 256, 0, stream>>>(Braw, graw, x, BwT, gamma_s, xT);
        inp_kernel<<<(BB * SS) / 4, 256, 0, stream>>>(x, BwT, inp);
        scan_fb_kernel<<<(BB * DD * NN) / 256, 256, 0, stream>>>(x, Araw, Craw, inp, out, hfin);
    }
    ln_kernel<<<(BB * SS * NN) / 256, 256, 0, stream>>>(x, gamma_s, out);
}